// Round 1
// baseline (928.104 us; speedup 1.0000x reference)
//
#include <hip/hip_runtime.h>

// ARMA GCN (K=2, two layers) on MI355X.
// Structure:
//   ew[e] = rsqrt(deg[src])*rsqrt(deg[dst]), deg over dst.
//   Layer1: h = mean_k relu( A@(x@iw1_k) + x@rw1_k + b1_k )   [N,16]
//   Layer2: out = mean_k relu( (A@h)@iw2_k + h@rw2_k + b2_k ) [N,40]
// Aggregation A@() commutes with the right-multiplies, so we propagate the
// 32-wide H1 = x@[iw1_0|iw1_1] and the 16-wide h (once), never anything wider.
// A is applied via CSR (edges bucketed by dst) pull — no float atomics.

#define TB 256

// ---------------- degree / norm ----------------
__global__ __launch_bounds__(TB) void k_deg(const int* __restrict__ dst,
                                            int* __restrict__ degi, int E) {
  int e = blockIdx.x * TB + threadIdx.x;
  if (e < E) atomicAdd(&degi[dst[e]], 1);
}

__global__ __launch_bounds__(TB) void k_dinv(const int* __restrict__ degi,
                                             float* __restrict__ dinv, int N) {
  int i = blockIdx.x * TB + threadIdx.x;
  if (i < N) {
    int d = degi[i];
    dinv[i] = d > 0 ? rsqrtf((float)d) : 0.0f;
  }
}

// ---------------- scan (exclusive prefix over degrees) ----------------
// 1024 elements per block.
__global__ __launch_bounds__(TB) void k_blocksum(const int* __restrict__ degi,
                                                 int* __restrict__ bsum, int N) {
  __shared__ int sh[TB];
  int tid = threadIdx.x;
  int base = blockIdx.x * 1024 + tid * 4;
  int s = 0;
#pragma unroll
  for (int c = 0; c < 4; c++) {
    int idx = base + c;
    if (idx < N) s += degi[idx];
  }
  sh[tid] = s;
  __syncthreads();
  for (int d = 128; d > 0; d >>= 1) {
    if (tid < d) sh[tid] += sh[tid + d];
    __syncthreads();
  }
  if (tid == 0) bsum[blockIdx.x] = sh[0];
}

__global__ __launch_bounds__(128) void k_scanbs(const int* __restrict__ bsum,
                                                int* __restrict__ boff, int NB) {
  __shared__ int sh[128];
  int tid = threadIdx.x;
  int v = (tid < NB) ? bsum[tid] : 0;
  sh[tid] = v;
  __syncthreads();
  for (int d = 1; d < 128; d <<= 1) {
    int t = (tid >= d) ? sh[tid - d] : 0;
    __syncthreads();
    sh[tid] += t;
    __syncthreads();
  }
  boff[tid] = sh[tid] - v;  // exclusive
}

__global__ __launch_bounds__(TB) void k_scanwrite(const int* __restrict__ degi,
                                                  const int* __restrict__ boff,
                                                  int* __restrict__ offsets,
                                                  int* __restrict__ cursor, int N) {
  __shared__ int sh[TB];
  int tid = threadIdx.x;
  int base = blockIdx.x * 1024 + tid * 4;
  int v[4];
  int s = 0;
#pragma unroll
  for (int c = 0; c < 4; c++) {
    int idx = base + c;
    v[c] = (idx < N) ? degi[idx] : 0;
    s += v[c];
  }
  sh[tid] = s;
  __syncthreads();
  for (int d = 1; d < TB; d <<= 1) {
    int t = (tid >= d) ? sh[tid - d] : 0;
    __syncthreads();
    sh[tid] += t;
    __syncthreads();
  }
  int run = sh[tid] - s + boff[blockIdx.x];
#pragma unroll
  for (int c = 0; c < 4; c++) {
    int idx = base + c;
    if (idx < N) {
      offsets[idx] = run;
      cursor[idx] = run;
      run += v[c];
    }
  }
}

// ---------------- CSR fill: (src, w) pairs bucketed by dst ----------------
__global__ __launch_bounds__(TB) void k_fill(const int* __restrict__ src,
                                             const int* __restrict__ dst,
                                             const float* __restrict__ dinv,
                                             int* __restrict__ cursor,
                                             int2* __restrict__ pairs, int E) {
  int e = blockIdx.x * TB + threadIdx.x;
  if (e < E) {
    int s = src[e], d = dst[e];
    float w = dinv[s] * dinv[d];
    int pos = atomicAdd(&cursor[d], 1);
    pairs[pos] = make_int2(s, __float_as_int(w));
  }
}

// ---------------- GEMM1: HR[n][0:32]=x@[iw1_0|iw1_1], HR[n][32:64]=x@[rw1_0|rw1_1]
// 64 rows x 64 cols per block, K=512 in chunks of 32, 4x4 register blocking.
__global__ __launch_bounds__(TB) void k_gemm1(const float* __restrict__ x,
                                              const float* __restrict__ iw1,
                                              const float* __restrict__ rw1,
                                              float* __restrict__ HR, int N) {
  __shared__ float xs[32 * 68];    // [k][row], row-dim padded 64->68 (16B-aligned quads)
  __shared__ float wsld[32 * 64];  // [k][col]
  int tid = threadIdx.x;
  int row0 = blockIdx.x * 64;
  int tc = tid & 15, tr = tid >> 4;
  float acc[4][4];
#pragma unroll
  for (int i = 0; i < 4; i++)
#pragma unroll
    for (int j = 0; j < 4; j++) acc[i][j] = 0.f;

  for (int kc = 0; kc < 512; kc += 32) {
    // stage x tile (transposed into [k][row])
#pragma unroll
    for (int it = 0; it < 2; it++) {
      int ql = it * 256 + tid;
      int row = ql >> 3, kq = ql & 7;
      int r = row0 + row;
      float4 v = make_float4(0.f, 0.f, 0.f, 0.f);
      if (r < N) v = *(const float4*)(x + (size_t)r * 512 + kc + kq * 4);
      xs[(kq * 4 + 0) * 68 + row] = v.x;
      xs[(kq * 4 + 1) * 68 + row] = v.y;
      xs[(kq * 4 + 2) * 68 + row] = v.z;
      xs[(kq * 4 + 3) * 68 + row] = v.w;
    }
    // stage weights [k][64] = [iw1_0 | iw1_1 | rw1_0 | rw1_1]
#pragma unroll
    for (int it = 0; it < 8; it++) {
      int idx = it * 256 + tid;
      int k = idx >> 6, j = idx & 63;
      int f = kc + k;
      float w;
      if (j < 16)
        w = iw1[f * 16 + j];
      else if (j < 32)
        w = iw1[8192 + f * 16 + (j - 16)];
      else if (j < 48)
        w = rw1[f * 16 + (j - 32)];
      else
        w = rw1[8192 + f * 16 + (j - 48)];
      wsld[k * 64 + j] = w;
    }
    __syncthreads();
#pragma unroll
    for (int k = 0; k < 32; k++) {
      float4 a4 = *(const float4*)&xs[k * 68 + tr * 4];
      float4 b4 = *(const float4*)&wsld[k * 64 + tc * 4];
      acc[0][0] += a4.x * b4.x; acc[0][1] += a4.x * b4.y; acc[0][2] += a4.x * b4.z; acc[0][3] += a4.x * b4.w;
      acc[1][0] += a4.y * b4.x; acc[1][1] += a4.y * b4.y; acc[1][2] += a4.y * b4.z; acc[1][3] += a4.y * b4.w;
      acc[2][0] += a4.z * b4.x; acc[2][1] += a4.z * b4.y; acc[2][2] += a4.z * b4.z; acc[2][3] += a4.z * b4.w;
      acc[3][0] += a4.w * b4.x; acc[3][1] += a4.w * b4.y; acc[3][2] += a4.w * b4.z; acc[3][3] += a4.w * b4.w;
    }
    __syncthreads();
  }
#pragma unroll
  for (int i = 0; i < 4; i++) {
    int r = row0 + tr * 4 + i;
    if (r < N) {
      float4 o = make_float4(acc[i][0], acc[i][1], acc[i][2], acc[i][3]);
      *(float4*)(HR + (size_t)r * 64 + tc * 4) = o;
    }
  }
}

// ---------------- prop1 (+ fused layer-1 epilogue): h = mean_k relu(A@H1 + R1 + b1)
// 8 lanes per node (one float4 quad of the 32-wide H1 each).
__global__ __launch_bounds__(TB) void k_prop1(const int* __restrict__ offsets,
                                              const int* __restrict__ degi,
                                              const int2* __restrict__ pairs,
                                              const float* __restrict__ HR,
                                              const float* __restrict__ b1,
                                              float* __restrict__ h, int N) {
  int tid = blockIdx.x * TB + threadIdx.x;
  int q = tid & 7;
  int n = tid >> 3;
  bool valid = n < N;
  int beg = valid ? offsets[n] : 0;
  int cnt = valid ? degi[n] : 0;
  float4 acc = make_float4(0.f, 0.f, 0.f, 0.f);
  for (int i = 0; i < cnt; i++) {
    int2 p = pairs[beg + i];
    float w = __int_as_float(p.y);
    float4 v = *(const float4*)(HR + (size_t)p.x * 64 + q * 4);
    acc.x += w * v.x; acc.y += w * v.y; acc.z += w * v.z; acc.w += w * v.w;
  }
  float4 r = make_float4(0.f, 0.f, 0.f, 0.f);
  if (valid) r = *(const float4*)(HR + (size_t)n * 64 + 32 + q * 4);
  int k = q >> 2, o4 = (q & 3) * 4;
  float4 b = *(const float4*)(b1 + k * 16 + o4);
  float4 v;
  v.x = fmaxf(acc.x + r.x + b.x, 0.f);
  v.y = fmaxf(acc.y + r.y + b.y, 0.f);
  v.z = fmaxf(acc.z + r.z + b.z, 0.f);
  v.w = fmaxf(acc.w + r.w + b.w, 0.f);
  // pair (k=0 quad q) with (k=1 quad q+4): lanes differ by 4
  float px = __shfl_xor(v.x, 4);
  float py = __shfl_xor(v.y, 4);
  float pz = __shfl_xor(v.z, 4);
  float pw = __shfl_xor(v.w, 4);
  if (valid && q < 4) {
    float4 hv = make_float4(0.5f * (v.x + px), 0.5f * (v.y + py),
                            0.5f * (v.z + pz), 0.5f * (v.w + pw));
    *(float4*)(h + (size_t)n * 16 + q * 4) = hv;
  }
}

// ---------------- prop2: Ah = A@h (16-wide, 4 lanes per node) ----------------
__global__ __launch_bounds__(TB) void k_prop2(const int* __restrict__ offsets,
                                              const int* __restrict__ degi,
                                              const int2* __restrict__ pairs,
                                              const float* __restrict__ h,
                                              float* __restrict__ Ah, int N) {
  int tid = blockIdx.x * TB + threadIdx.x;
  int q = tid & 3;
  int n = tid >> 2;
  if (n >= N) return;
  int beg = offsets[n];
  int cnt = degi[n];
  float4 acc = make_float4(0.f, 0.f, 0.f, 0.f);
  for (int i = 0; i < cnt; i++) {
    int2 p = pairs[beg + i];
    float w = __int_as_float(p.y);
    float4 v = *(const float4*)(h + (size_t)p.x * 16 + q * 4);
    acc.x += w * v.x; acc.y += w * v.y; acc.z += w * v.z; acc.w += w * v.w;
  }
  *(float4*)(Ah + (size_t)n * 16 + q * 4) = acc;
}

// ---------------- final: out = mean_k relu(Ah@iw2_k + h@rw2_k + b2_k) ----------------
__global__ __launch_bounds__(TB) void k_final(const float* __restrict__ Ah,
                                              const float* __restrict__ h,
                                              const float* __restrict__ iw2,
                                              const float* __restrict__ rw2,
                                              const float* __restrict__ b2,
                                              float* __restrict__ out, int N) {
  __shared__ float w_iw[2 * 16 * 40];
  __shared__ float w_rw[2 * 16 * 40];
  __shared__ float w_b[2 * 40];
  for (int i = threadIdx.x; i < 1280; i += TB) {
    w_iw[i] = iw2[i];
    w_rw[i] = rw2[i];
  }
  for (int i = threadIdx.x; i < 80; i += TB) w_b[i] = b2[i];
  __syncthreads();

  int idx = blockIdx.x * TB + threadIdx.x;
  if (idx >= N * 40) return;
  int n = idx / 40;
  int o = idx - n * 40;
  float a[16], hr[16];
#pragma unroll
  for (int f = 0; f < 16; f++) {
    a[f] = Ah[(size_t)n * 16 + f];
    hr[f] = h[(size_t)n * 16 + f];
  }
  float res = 0.f;
#pragma unroll
  for (int k = 0; k < 2; k++) {
    float s = w_b[k * 40 + o];
#pragma unroll
    for (int f = 0; f < 16; f++) {
      s += a[f] * w_iw[(k * 16 + f) * 40 + o];
      s += hr[f] * w_rw[(k * 16 + f) * 40 + o];
    }
    res += fmaxf(s, 0.f);
  }
  out[idx] = 0.5f * res;
}

extern "C" void kernel_launch(void* const* d_in, const int* in_sizes, int n_in,
                              void* d_out, int out_size, void* d_ws, size_t ws_size,
                              hipStream_t stream) {
  const float* x = (const float*)d_in[0];
  const int* ei = (const int*)d_in[1];
  const float* iw1 = (const float*)d_in[2];
  const float* rw1 = (const float*)d_in[3];
  const float* b1 = (const float*)d_in[4];
  const float* iw2 = (const float*)d_in[5];
  const float* rw2 = (const float*)d_in[6];
  const float* b2 = (const float*)d_in[7];
  float* out = (float*)d_out;

  const int N = in_sizes[0] / 512;
  const int E = in_sizes[1] / 2;
  const int* src = ei;
  const int* dst = ei + E;

  char* base = (char*)d_ws;
  size_t off = 0;
  auto alloc = [&](size_t bytes) -> void* {
    off = (off + 255) & ~(size_t)255;
    void* p = base + off;
    off += bytes;
    return p;
  };
  int* degi = (int*)alloc((size_t)N * 4);
  float* dinv = (float*)alloc((size_t)N * 4);
  int* offsets = (int*)alloc((size_t)N * 4);
  int* cursor = (int*)alloc((size_t)N * 4);
  int* bsum = (int*)alloc(128 * 4);
  int* boff = (int*)alloc(128 * 4);
  int2* pairs = (int2*)alloc((size_t)E * 8);
  float* HR = (float*)alloc((size_t)N * 64 * 4);
  float* hbuf = (float*)alloc((size_t)N * 16 * 4);
  float* Ah = (float*)alloc((size_t)N * 16 * 4);
  (void)ws_size;

  hipMemsetAsync(degi, 0, (size_t)N * 4, stream);

  int NB = (N + 1023) / 1024;
  k_deg<<<(E + TB - 1) / TB, TB, 0, stream>>>(dst, degi, E);
  k_dinv<<<(N + TB - 1) / TB, TB, 0, stream>>>(degi, dinv, N);
  k_blocksum<<<NB, TB, 0, stream>>>(degi, bsum, N);
  k_scanbs<<<1, 128, 0, stream>>>(bsum, boff, NB);
  k_scanwrite<<<NB, TB, 0, stream>>>(degi, boff, offsets, cursor, N);
  k_fill<<<(E + TB - 1) / TB, TB, 0, stream>>>(src, dst, dinv, cursor, pairs, E);
  k_gemm1<<<(N + 63) / 64, TB, 0, stream>>>(x, iw1, rw1, HR, N);
  k_prop1<<<(N * 8 + TB - 1) / TB, TB, 0, stream>>>(offsets, degi, pairs, HR, b1, hbuf, N);
  k_prop2<<<(N * 4 + TB - 1) / TB, TB, 0, stream>>>(offsets, degi, pairs, hbuf, Ah, N);
  k_final<<<((size_t)N * 40 + TB - 1) / TB, TB, 0, stream>>>(Ah, hbuf, iw2, rw2, b2, out, N);
}

// Round 2
// 779.732 us; speedup vs baseline: 1.1903x; 1.1903x over previous
//
#include <hip/hip_runtime.h>

// ARMA GCN (K=2, two layers) on MI355X.
//   Layer1: h = mean_k relu( A@(x@iw1_k) + x@rw1_k + b1_k )   [N,16]
//   Layer2: out = mean_k relu( (A@h)@iw2_k + h@rw2_k + b2_k ) [N,40]
// Aggregation commutes with right-multiplies: propagate 32-wide H1 and 16-wide h.
// A applied via CSR (edges bucketed by dst) pull — no float atomics.
// GEMM1 (100000x512 @ 512x64) via bf16 MFMA with 3-term hi/lo split (~fp32 acc.):
// barrier-free, LDS-free; A-frags loaded global->reg in fragment order, B-frags
// pre-split into fragment-ordered hi/lo bf16 tables (L2-resident).

#define TB 256

typedef __attribute__((ext_vector_type(8))) short bf8;
typedef __attribute__((ext_vector_type(4))) float f4;

__device__ inline unsigned short f2bf_rne(float f) {
  unsigned int u = __float_as_uint(f);
  unsigned int r = u + 0x7fffu + ((u >> 16) & 1u);
  return (unsigned short)(r >> 16);
}
__device__ inline float bf2f(unsigned short h) {
  return __uint_as_float(((unsigned int)h) << 16);
}

// ---------------- degree / norm ----------------
__global__ __launch_bounds__(TB) void k_deg(const int* __restrict__ dst,
                                            int* __restrict__ degi, int E) {
  int e = blockIdx.x * TB + threadIdx.x;
  if (e < E) atomicAdd(&degi[dst[e]], 1);
}

__global__ __launch_bounds__(TB) void k_dinv(const int* __restrict__ degi,
                                             float* __restrict__ dinv, int N) {
  int i = blockIdx.x * TB + threadIdx.x;
  if (i < N) {
    int d = degi[i];
    dinv[i] = d > 0 ? rsqrtf((float)d) : 0.0f;
  }
}

// ---------------- scan (exclusive prefix over degrees) ----------------
__global__ __launch_bounds__(TB) void k_blocksum(const int* __restrict__ degi,
                                                 int* __restrict__ bsum, int N) {
  __shared__ int sh[TB];
  int tid = threadIdx.x;
  int base = blockIdx.x * 1024 + tid * 4;
  int s = 0;
#pragma unroll
  for (int c = 0; c < 4; c++) {
    int idx = base + c;
    if (idx < N) s += degi[idx];
  }
  sh[tid] = s;
  __syncthreads();
  for (int d = 128; d > 0; d >>= 1) {
    if (tid < d) sh[tid] += sh[tid + d];
    __syncthreads();
  }
  if (tid == 0) bsum[blockIdx.x] = sh[0];
}

__global__ __launch_bounds__(128) void k_scanbs(const int* __restrict__ bsum,
                                                int* __restrict__ boff, int NB) {
  __shared__ int sh[128];
  int tid = threadIdx.x;
  int v = (tid < NB) ? bsum[tid] : 0;
  sh[tid] = v;
  __syncthreads();
  for (int d = 1; d < 128; d <<= 1) {
    int t = (tid >= d) ? sh[tid - d] : 0;
    __syncthreads();
    sh[tid] += t;
    __syncthreads();
  }
  boff[tid] = sh[tid] - v;  // exclusive
}

__global__ __launch_bounds__(TB) void k_scanwrite(const int* __restrict__ degi,
                                                  const int* __restrict__ boff,
                                                  int* __restrict__ offsets,
                                                  int* __restrict__ cursor, int N) {
  __shared__ int sh[TB];
  int tid = threadIdx.x;
  int base = blockIdx.x * 1024 + tid * 4;
  int v[4];
  int s = 0;
#pragma unroll
  for (int c = 0; c < 4; c++) {
    int idx = base + c;
    v[c] = (idx < N) ? degi[idx] : 0;
    s += v[c];
  }
  sh[tid] = s;
  __syncthreads();
  for (int d = 1; d < TB; d <<= 1) {
    int t = (tid >= d) ? sh[tid - d] : 0;
    __syncthreads();
    sh[tid] += t;
    __syncthreads();
  }
  int run = sh[tid] - s + boff[blockIdx.x];
#pragma unroll
  for (int c = 0; c < 4; c++) {
    int idx = base + c;
    if (idx < N) {
      offsets[idx] = run;
      cursor[idx] = run;
      run += v[c];
    }
  }
}

// ---------------- CSR fill: (src, w) pairs bucketed by dst ----------------
__global__ __launch_bounds__(TB) void k_fill(const int* __restrict__ src,
                                             const int* __restrict__ dst,
                                             const float* __restrict__ dinv,
                                             int* __restrict__ cursor,
                                             int2* __restrict__ pairs, int E) {
  int e = blockIdx.x * TB + threadIdx.x;
  if (e < E) {
    int s = src[e], d = dst[e];
    float w = dinv[s] * dinv[d];
    int pos = atomicAdd(&cursor[d], 1);
    pairs[pos] = make_int2(s, __float_as_int(w));
  }
}

// ---------------- weight split: fragment-ordered hi/lo bf16 tables ----------
// Element (c,t,l,j): B[k = c*32 + (l>>4)*8 + j][n = t*16 + (l&15)],
// flat idx = ((c*4+t)*64 + l)*8 + j.  Cols: [iw1_s0 | iw1_s1 | rw1_s0 | rw1_s1].
__global__ __launch_bounds__(TB) void k_wsplit(const float* __restrict__ iw1,
                                               const float* __restrict__ rw1,
                                               short* __restrict__ Whi,
                                               short* __restrict__ Wlo) {
  int idx = blockIdx.x * TB + threadIdx.x;
  if (idx >= 32768) return;
  int j = idx & 7;
  int l = (idx >> 3) & 63;
  int t = (idx >> 9) & 3;
  int c = idx >> 11;
  int k = c * 32 + (l >> 4) * 8 + j;
  int n = t * 16 + (l & 15);
  float w;
  if (n < 16)
    w = iw1[k * 16 + n];
  else if (n < 32)
    w = iw1[8192 + k * 16 + (n - 16)];
  else if (n < 48)
    w = rw1[k * 16 + (n - 32)];
  else
    w = rw1[8192 + k * 16 + (n - 48)];
  unsigned short h = f2bf_rne(w);
  float res = w - bf2f(h);
  Whi[idx] = (short)h;
  Wlo[idx] = (short)f2bf_rne(res);
}

// ---------------- GEMM1 via MFMA: HR[N,64] = x @ [iw1_0|iw1_1|rw1_0|rw1_1] ----
// Per wave: 16 rows x 64 cols, K=512 in 16 chunks of 32. No LDS, no barriers.
// 3-term split: x_hi*W_hi + x_lo*W_hi + x_hi*W_lo  (error ~2^-17 rel).
__global__ __launch_bounds__(TB) void k_gemm1_mfma(const float* __restrict__ x,
                                                   const short* __restrict__ Whi,
                                                   const short* __restrict__ Wlo,
                                                   float* __restrict__ HR, int N) {
  int lane = threadIdx.x & 63;
  int wave = threadIdx.x >> 6;
  int row0 = blockIdx.x * 64 + wave * 16;
  int m = lane & 15, quad = lane >> 4;
  int r = row0 + m;
  bool rv = (r < N);
  const float* xr = x + (size_t)r * 512;

  f4 acc[4];
#pragma unroll
  for (int t = 0; t < 4; t++) acc[t] = (f4){0.f, 0.f, 0.f, 0.f};

  for (int c = 0; c < 16; ++c) {
    float xv[8];
    if (rv) {
      f4 a0 = *(const f4*)(xr + c * 32 + quad * 8);
      f4 a1 = *(const f4*)(xr + c * 32 + quad * 8 + 4);
      xv[0] = a0.x; xv[1] = a0.y; xv[2] = a0.z; xv[3] = a0.w;
      xv[4] = a1.x; xv[5] = a1.y; xv[6] = a1.z; xv[7] = a1.w;
    } else {
#pragma unroll
      for (int j = 0; j < 8; ++j) xv[j] = 0.f;
    }
    bf8 ahi, alo;
#pragma unroll
    for (int j = 0; j < 8; ++j) {
      unsigned short h = f2bf_rne(xv[j]);
      float res = xv[j] - bf2f(h);
      ahi[j] = (short)h;
      alo[j] = (short)f2bf_rne(res);
    }
    const short* wb = Whi + ((size_t)(c * 4) * 64 + lane) * 8;
    const short* wl = Wlo + ((size_t)(c * 4) * 64 + lane) * 8;
#pragma unroll
    for (int t = 0; t < 4; ++t) {
      bf8 bh = *(const bf8*)(wb + t * 512);
      bf8 bl = *(const bf8*)(wl + t * 512);
      acc[t] = __builtin_amdgcn_mfma_f32_16x16x32_bf16(ahi, bh, acc[t], 0, 0, 0);
      acc[t] = __builtin_amdgcn_mfma_f32_16x16x32_bf16(alo, bh, acc[t], 0, 0, 0);
      acc[t] = __builtin_amdgcn_mfma_f32_16x16x32_bf16(ahi, bl, acc[t], 0, 0, 0);
    }
  }
  // C/D layout: col = t*16 + (lane&15), row = quad*4 + reg
#pragma unroll
  for (int t = 0; t < 4; ++t) {
#pragma unroll
    for (int g = 0; g < 4; ++g) {
      int ro = row0 + quad * 4 + g;
      if (ro < N) HR[(size_t)ro * 64 + t * 16 + m] = acc[t][g];
    }
  }
}

// ---------------- prop1 (+ fused layer-1 epilogue): h = mean_k relu(A@H1 + R1 + b1)
__global__ __launch_bounds__(TB) void k_prop1(const int* __restrict__ offsets,
                                              const int* __restrict__ degi,
                                              const int2* __restrict__ pairs,
                                              const float* __restrict__ HR,
                                              const float* __restrict__ b1,
                                              float* __restrict__ h, int N) {
  int tid = blockIdx.x * TB + threadIdx.x;
  int q = tid & 7;
  int n = tid >> 3;
  bool valid = n < N;
  int beg = valid ? offsets[n] : 0;
  int cnt = valid ? degi[n] : 0;
  float4 acc = make_float4(0.f, 0.f, 0.f, 0.f);
  for (int i = 0; i < cnt; i++) {
    int2 p = pairs[beg + i];
    float w = __int_as_float(p.y);
    float4 v = *(const float4*)(HR + (size_t)p.x * 64 + q * 4);
    acc.x += w * v.x; acc.y += w * v.y; acc.z += w * v.z; acc.w += w * v.w;
  }
  float4 r = make_float4(0.f, 0.f, 0.f, 0.f);
  if (valid) r = *(const float4*)(HR + (size_t)n * 64 + 32 + q * 4);
  int k = q >> 2, o4 = (q & 3) * 4;
  float4 b = *(const float4*)(b1 + k * 16 + o4);
  float4 v;
  v.x = fmaxf(acc.x + r.x + b.x, 0.f);
  v.y = fmaxf(acc.y + r.y + b.y, 0.f);
  v.z = fmaxf(acc.z + r.z + b.z, 0.f);
  v.w = fmaxf(acc.w + r.w + b.w, 0.f);
  float px = __shfl_xor(v.x, 4);
  float py = __shfl_xor(v.y, 4);
  float pz = __shfl_xor(v.z, 4);
  float pw = __shfl_xor(v.w, 4);
  if (valid && q < 4) {
    float4 hv = make_float4(0.5f * (v.x + px), 0.5f * (v.y + py),
                            0.5f * (v.z + pz), 0.5f * (v.w + pw));
    *(float4*)(h + (size_t)n * 16 + q * 4) = hv;
  }
}

// ---------------- prop2: Ah = A@h ----------------
__global__ __launch_bounds__(TB) void k_prop2(const int* __restrict__ offsets,
                                              const int* __restrict__ degi,
                                              const int2* __restrict__ pairs,
                                              const float* __restrict__ h,
                                              float* __restrict__ Ah, int N) {
  int tid = blockIdx.x * TB + threadIdx.x;
  int q = tid & 3;
  int n = tid >> 2;
  if (n >= N) return;
  int beg = offsets[n];
  int cnt = degi[n];
  float4 acc = make_float4(0.f, 0.f, 0.f, 0.f);
  for (int i = 0; i < cnt; i++) {
    int2 p = pairs[beg + i];
    float w = __int_as_float(p.y);
    float4 v = *(const float4*)(h + (size_t)p.x * 16 + q * 4);
    acc.x += w * v.x; acc.y += w * v.y; acc.z += w * v.z; acc.w += w * v.w;
  }
  *(float4*)(Ah + (size_t)n * 16 + q * 4) = acc;
}

// ---------------- final: out = mean_k relu(Ah@iw2_k + h@rw2_k + b2_k) --------
__global__ __launch_bounds__(TB) void k_final(const float* __restrict__ Ah,
                                              const float* __restrict__ h,
                                              const float* __restrict__ iw2,
                                              const float* __restrict__ rw2,
                                              const float* __restrict__ b2,
                                              float* __restrict__ out, int N) {
  __shared__ float w_iw[2 * 16 * 40];
  __shared__ float w_rw[2 * 16 * 40];
  __shared__ float w_b[2 * 40];
  for (int i = threadIdx.x; i < 1280; i += TB) {
    w_iw[i] = iw2[i];
    w_rw[i] = rw2[i];
  }
  for (int i = threadIdx.x; i < 80; i += TB) w_b[i] = b2[i];
  __syncthreads();

  int idx = blockIdx.x * TB + threadIdx.x;
  if (idx >= N * 40) return;
  int n = idx / 40;
  int o = idx - n * 40;
  float a[16], hr[16];
#pragma unroll
  for (int f = 0; f < 16; f++) {
    a[f] = Ah[(size_t)n * 16 + f];
    hr[f] = h[(size_t)n * 16 + f];
  }
  float res = 0.f;
#pragma unroll
  for (int k = 0; k < 2; k++) {
    float s = w_b[k * 40 + o];
#pragma unroll
    for (int f = 0; f < 16; f++) {
      s += a[f] * w_iw[(k * 16 + f) * 40 + o];
      s += hr[f] * w_rw[(k * 16 + f) * 40 + o];
    }
    res += fmaxf(s, 0.f);
  }
  out[idx] = 0.5f * res;
}

extern "C" void kernel_launch(void* const* d_in, const int* in_sizes, int n_in,
                              void* d_out, int out_size, void* d_ws, size_t ws_size,
                              hipStream_t stream) {
  const float* x = (const float*)d_in[0];
  const int* ei = (const int*)d_in[1];
  const float* iw1 = (const float*)d_in[2];
  const float* rw1 = (const float*)d_in[3];
  const float* b1 = (const float*)d_in[4];
  const float* iw2 = (const float*)d_in[5];
  const float* rw2 = (const float*)d_in[6];
  const float* b2 = (const float*)d_in[7];
  float* out = (float*)d_out;

  const int N = in_sizes[0] / 512;
  const int E = in_sizes[1] / 2;
  const int* src = ei;
  const int* dst = ei + E;

  char* base = (char*)d_ws;
  size_t off = 0;
  auto alloc = [&](size_t bytes) -> void* {
    off = (off + 255) & ~(size_t)255;
    void* p = base + off;
    off += bytes;
    return p;
  };
  int* degi = (int*)alloc((size_t)N * 4);
  float* dinv = (float*)alloc((size_t)N * 4);
  int* offsets = (int*)alloc((size_t)N * 4);
  int* cursor = (int*)alloc((size_t)N * 4);
  int* bsum = (int*)alloc(128 * 4);
  int* boff = (int*)alloc(128 * 4);
  int2* pairs = (int2*)alloc((size_t)E * 8);
  float* HR = (float*)alloc((size_t)N * 64 * 4);
  float* hbuf = (float*)alloc((size_t)N * 16 * 4);
  float* Ah = (float*)alloc((size_t)N * 16 * 4);
  short* Whi = (short*)alloc(32768 * 2);
  short* Wlo = (short*)alloc(32768 * 2);
  (void)ws_size;

  hipMemsetAsync(degi, 0, (size_t)N * 4, stream);

  int NB = (N + 1023) / 1024;
  k_wsplit<<<128, TB, 0, stream>>>(iw1, rw1, Whi, Wlo);
  k_deg<<<(E + TB - 1) / TB, TB, 0, stream>>>(dst, degi, E);
  k_dinv<<<(N + TB - 1) / TB, TB, 0, stream>>>(degi, dinv, N);
  k_blocksum<<<NB, TB, 0, stream>>>(degi, bsum, N);
  k_scanbs<<<1, 128, 0, stream>>>(bsum, boff, NB);
  k_scanwrite<<<NB, TB, 0, stream>>>(degi, boff, offsets, cursor, N);
  k_fill<<<(E + TB - 1) / TB, TB, 0, stream>>>(src, dst, dinv, cursor, pairs, E);
  k_gemm1_mfma<<<(N + 63) / 64, TB, 0, stream>>>(x, Whi, Wlo, HR, N);
  k_prop1<<<(N * 8 + TB - 1) / TB, TB, 0, stream>>>(offsets, degi, pairs, HR, b1, hbuf, N);
  k_prop2<<<(N * 4 + TB - 1) / TB, TB, 0, stream>>>(offsets, degi, pairs, hbuf, Ah, N);
  k_final<<<((size_t)N * 40 + TB - 1) / TB, TB, 0, stream>>>(Ah, hbuf, iw2, rw2, b2, out, N);
}

// Round 3
// 604.210 us; speedup vs baseline: 1.5361x; 1.2905x over previous
//
#include <hip/hip_runtime.h>

// ARMA GCN (K=2, two layers) on MI355X.
//   Layer1: h = mean_k relu( A@(x@iw1_k) + x@rw1_k + b1_k )   [N,16]
//   Layer2: out = mean_k relu( (A@h)@iw2_k + h@rw2_k + b2_k ) [N,40]
// - Aggregation commutes with right-multiplies: propagate 32-wide H1, 16-wide h.
// - dinv folded symmetrically: Hs = dinv*H1 stored bf16, pull sums then *dinv[n].
// - CSR build = 2-pass radix partition by dst (coarse 512-node buckets, then
//   exact within-bucket via LDS scan). No global float atomics, no 64B-line
//   write amplification (R1's k_fill wrote 200MB for a 25.6MB array).
// - GEMM1 via bf16 MFMA 3-term hi/lo split (~fp32 accuracy), LDS/barrier-free.

#define TB 256
#define CHA 4096  // edges per block in count/binA passes

typedef __attribute__((ext_vector_type(8))) short bf8;
typedef __attribute__((ext_vector_type(4))) float f4;

__device__ inline unsigned short f2bf_rne(float f) {
  unsigned int u = __float_as_uint(f);
  unsigned int r = u + 0x7fffu + ((u >> 16) & 1u);
  return (unsigned short)(r >> 16);
}
__device__ inline float bf2f(unsigned short h) {
  return __uint_as_float(((unsigned int)h) << 16);
}
__device__ inline float bflo(unsigned int u) { return __uint_as_float(u << 16); }
__device__ inline float bfhi(unsigned int u) { return __uint_as_float(u & 0xffff0000u); }
__device__ inline unsigned int bfpack(float lo, float hi) {
  return (unsigned int)f2bf_rne(lo) | ((unsigned int)f2bf_rne(hi) << 16);
}

// ---------------- pass 0: coarse histogram (bucket = dst>>9) ----------------
__global__ __launch_bounds__(TB) void k_countA(const int* __restrict__ dst,
                                               int* __restrict__ ccnt, int E) {
  __shared__ int cnt[256];
  int tid = threadIdx.x;
  cnt[tid] = 0;
  __syncthreads();
  int e0 = blockIdx.x * CHA;
  int e1 = min(e0 + CHA, E);
  for (int e = e0 + tid; e < e1; e += TB) atomicAdd(&cnt[dst[e] >> 9], 1);
  __syncthreads();
  if (cnt[tid] > 0) atomicAdd(&ccnt[tid], cnt[tid]);
}

// ---------------- pass 0b: scan 256 coarse counts ----------------
__global__ __launch_bounds__(256) void k_scanC(const int* __restrict__ ccnt,
                                               int* __restrict__ cbase,
                                               int* __restrict__ ccur) {
  __shared__ int sh[256];
  int tid = threadIdx.x;
  int v = ccnt[tid];
  sh[tid] = v;
  __syncthreads();
  for (int d = 1; d < 256; d <<= 1) {
    int t = (tid >= d) ? sh[tid - d] : 0;
    __syncthreads();
    sh[tid] += t;
    __syncthreads();
  }
  int excl = sh[tid] - v;
  cbase[tid] = excl;
  ccur[tid] = excl;
  if (tid == 255) cbase[256] = sh[255];  // total = E
}

// ---------------- pass 1: partition (src,dst) into coarse buckets ----------
__global__ __launch_bounds__(TB) void k_binA(const int* __restrict__ src,
                                             const int* __restrict__ dst,
                                             int* __restrict__ ccur,
                                             int2* __restrict__ epairs, int E) {
  __shared__ int cnt[256];
  __shared__ int gb[256];
  int tid = threadIdx.x;
  cnt[tid] = 0;
  __syncthreads();
  int e0 = blockIdx.x * CHA;
  int e1 = min(e0 + CHA, E);
  for (int e = e0 + tid; e < e1; e += TB) atomicAdd(&cnt[dst[e] >> 9], 1);
  __syncthreads();
  int c = cnt[tid];
  if (c > 0) gb[tid] = atomicAdd(&ccur[tid], c);
  __syncthreads();
  cnt[tid] = 0;
  __syncthreads();
  for (int e = e0 + tid; e < e1; e += TB) {
    int dv = dst[e];
    int b = dv >> 9;
    int r = atomicAdd(&cnt[b], 1);
    epairs[gb[b] + r] = make_int2(src[e], dv);
  }
}

// ---------------- pass 2: exact CSR within each 512-node bucket -------------
// Produces degi, offsets, and srcs (4B per edge). No global atomics.
__global__ __launch_bounds__(TB) void k_binB(const int2* __restrict__ epairs,
                                             const int* __restrict__ cbase,
                                             int* __restrict__ degi,
                                             int* __restrict__ offsets,
                                             int* __restrict__ srcs, int N) {
  __shared__ int cnt[512];
  __shared__ int pre[512];
  int b = blockIdx.x;
  int n0 = b << 9;
  int tid = threadIdx.x;
  int beg = cbase[b], end = cbase[b + 1];
  int i0 = tid, i1 = tid + 256;
  cnt[i0] = 0; cnt[i1] = 0;
  __syncthreads();
  for (int e = beg + tid; e < end; e += TB) atomicAdd(&cnt[epairs[e].y - n0], 1);
  __syncthreads();
  pre[i0] = cnt[i0]; pre[i1] = cnt[i1];
  __syncthreads();
  for (int d = 1; d < 512; d <<= 1) {
    int t0 = (i0 >= d) ? pre[i0 - d] : 0;
    int t1 = (i1 >= d) ? pre[i1 - d] : 0;
    __syncthreads();
    pre[i0] += t0; pre[i1] += t1;
    __syncthreads();
  }
  int e0 = pre[i0] - cnt[i0];
  int e1x = pre[i1] - cnt[i1];
  if (n0 + i0 < N) { degi[n0 + i0] = cnt[i0]; offsets[n0 + i0] = beg + e0; }
  if (n0 + i1 < N) { degi[n0 + i1] = cnt[i1]; offsets[n0 + i1] = beg + e1x; }
  __syncthreads();
  cnt[i0] = e0; cnt[i1] = e1x;  // reuse as cursors
  __syncthreads();
  for (int e = beg + tid; e < end; e += TB) {
    int2 p = epairs[e];
    int pos = atomicAdd(&cnt[p.y - n0], 1);
    srcs[beg + pos] = p.x;
  }
}

__global__ __launch_bounds__(TB) void k_dinv(const int* __restrict__ degi,
                                             float* __restrict__ dinv, int N) {
  int i = blockIdx.x * TB + threadIdx.x;
  if (i < N) {
    int d = degi[i];
    dinv[i] = d > 0 ? rsqrtf((float)d) : 0.0f;
  }
}

// ---------------- weight split: fragment-ordered hi/lo bf16 tables ----------
__global__ __launch_bounds__(TB) void k_wsplit(const float* __restrict__ iw1,
                                               const float* __restrict__ rw1,
                                               short* __restrict__ Whi,
                                               short* __restrict__ Wlo) {
  int idx = blockIdx.x * TB + threadIdx.x;
  if (idx >= 32768) return;
  int j = idx & 7;
  int l = (idx >> 3) & 63;
  int t = (idx >> 9) & 3;
  int c = idx >> 11;
  int k = c * 32 + (l >> 4) * 8 + j;
  int n = t * 16 + (l & 15);
  float w;
  if (n < 16)
    w = iw1[k * 16 + n];
  else if (n < 32)
    w = iw1[8192 + k * 16 + (n - 16)];
  else if (n < 48)
    w = rw1[k * 16 + (n - 32)];
  else
    w = rw1[8192 + k * 16 + (n - 48)];
  unsigned short h = f2bf_rne(w);
  float res = w - bf2f(h);
  Whi[idx] = (short)h;
  Wlo[idx] = (short)f2bf_rne(res);
}

// ---------------- GEMM1 via MFMA ----------------
// Hs[N,32] bf16 = dinv[n] * x@[iw1_0|iw1_1];  R[N,32] fp32 = x@[rw1_0|rw1_1].
__global__ __launch_bounds__(TB) void k_gemm1_mfma(const float* __restrict__ x,
                                                   const short* __restrict__ Whi,
                                                   const short* __restrict__ Wlo,
                                                   const float* __restrict__ dinv,
                                                   unsigned short* __restrict__ Hs,
                                                   float* __restrict__ R, int N) {
  int lane = threadIdx.x & 63;
  int wave = threadIdx.x >> 6;
  int row0 = blockIdx.x * 64 + wave * 16;
  int m = lane & 15, quad = lane >> 4;
  int r = row0 + m;
  bool rv = (r < N);
  const float* xr = x + (size_t)r * 512;

  f4 acc[4];
#pragma unroll
  for (int t = 0; t < 4; t++) acc[t] = (f4){0.f, 0.f, 0.f, 0.f};

  for (int c = 0; c < 16; ++c) {
    float xv[8];
    if (rv) {
      f4 a0 = *(const f4*)(xr + c * 32 + quad * 8);
      f4 a1 = *(const f4*)(xr + c * 32 + quad * 8 + 4);
      xv[0] = a0.x; xv[1] = a0.y; xv[2] = a0.z; xv[3] = a0.w;
      xv[4] = a1.x; xv[5] = a1.y; xv[6] = a1.z; xv[7] = a1.w;
    } else {
#pragma unroll
      for (int j = 0; j < 8; ++j) xv[j] = 0.f;
    }
    bf8 ahi, alo;
#pragma unroll
    for (int j = 0; j < 8; ++j) {
      unsigned short h = f2bf_rne(xv[j]);
      float res = xv[j] - bf2f(h);
      ahi[j] = (short)h;
      alo[j] = (short)f2bf_rne(res);
    }
    const short* wb = Whi + ((size_t)(c * 4) * 64 + lane) * 8;
    const short* wl = Wlo + ((size_t)(c * 4) * 64 + lane) * 8;
#pragma unroll
    for (int t = 0; t < 4; ++t) {
      bf8 bh = *(const bf8*)(wb + t * 512);
      bf8 bl = *(const bf8*)(wl + t * 512);
      acc[t] = __builtin_amdgcn_mfma_f32_16x16x32_bf16(ahi, bh, acc[t], 0, 0, 0);
      acc[t] = __builtin_amdgcn_mfma_f32_16x16x32_bf16(alo, bh, acc[t], 0, 0, 0);
      acc[t] = __builtin_amdgcn_mfma_f32_16x16x32_bf16(ahi, bl, acc[t], 0, 0, 0);
    }
  }
  // C/D layout: col = t*16 + m, row = quad*4 + g
  float dv[4];
#pragma unroll
  for (int g = 0; g < 4; ++g) {
    int ro = row0 + quad * 4 + g;
    dv[g] = (ro < N) ? dinv[ro] : 0.f;
  }
#pragma unroll
  for (int t = 0; t < 4; ++t) {
#pragma unroll
    for (int g = 0; g < 4; ++g) {
      int ro = row0 + quad * 4 + g;
      if (ro < N) {
        if (t < 2)
          Hs[(size_t)ro * 32 + t * 16 + m] = f2bf_rne(acc[t][g] * dv[g]);
        else
          R[(size_t)ro * 32 + (t - 2) * 16 + m] = acc[t][g];
      }
    }
  }
}

// ---------------- prop1: h = mean_k relu(dinv[n]*sum Hs[src] + R + b1) -------
// 4 lanes per node, 8 features each; gathers 16B bf16x8 per edge per lane.
__global__ __launch_bounds__(TB) void k_prop1(const int* __restrict__ offsets,
                                              const int* __restrict__ degi,
                                              const int* __restrict__ srcs,
                                              const unsigned short* __restrict__ Hs,
                                              const float* __restrict__ R,
                                              const float* __restrict__ dinv,
                                              const float* __restrict__ b1,
                                              float* __restrict__ h,
                                              unsigned short* __restrict__ hs, int N) {
  int tid = blockIdx.x * TB + threadIdx.x;
  int q = tid & 3;
  int n = tid >> 2;
  if (n >= N) return;
  int beg = offsets[n], cnt = degi[n];
  float a[8];
#pragma unroll
  for (int j = 0; j < 8; j++) a[j] = 0.f;
  for (int i = 0; i < cnt; i++) {
    int s = srcs[beg + i];
    uint4 v = *(const uint4*)(Hs + (size_t)s * 32 + q * 8);
    a[0] += bflo(v.x); a[1] += bfhi(v.x);
    a[2] += bflo(v.y); a[3] += bfhi(v.y);
    a[4] += bflo(v.z); a[5] += bfhi(v.z);
    a[6] += bflo(v.w); a[7] += bfhi(v.w);
  }
  float dvn = dinv[n];
  f4 r0 = *(const f4*)(R + (size_t)n * 32 + q * 8);
  f4 r1 = *(const f4*)(R + (size_t)n * 32 + q * 8 + 4);
  float rr[8] = {r0.x, r0.y, r0.z, r0.w, r1.x, r1.y, r1.z, r1.w};
  float vv[8];
#pragma unroll
  for (int j = 0; j < 8; j++) {
    int f = q * 8 + j;
    vv[j] = fmaxf(a[j] * dvn + rr[j] + b1[(f >> 4) * 16 + (f & 15)], 0.f);
  }
  float pv[8];
#pragma unroll
  for (int j = 0; j < 8; j++) pv[j] = __shfl_xor(vv[j], 2);
  if (q < 2) {
    float hv[8];
#pragma unroll
    for (int j = 0; j < 8; j++) hv[j] = 0.5f * (vv[j] + pv[j]);
    f4 o0 = {hv[0], hv[1], hv[2], hv[3]};
    f4 o1 = {hv[4], hv[5], hv[6], hv[7]};
    *(f4*)(h + (size_t)n * 16 + q * 8) = o0;
    *(f4*)(h + (size_t)n * 16 + q * 8 + 4) = o1;
    uint4 ob;
    ob.x = bfpack(hv[0] * dvn, hv[1] * dvn);
    ob.y = bfpack(hv[2] * dvn, hv[3] * dvn);
    ob.z = bfpack(hv[4] * dvn, hv[5] * dvn);
    ob.w = bfpack(hv[6] * dvn, hv[7] * dvn);
    *(uint4*)(hs + (size_t)n * 16 + q * 8) = ob;
  }
}

// ---------------- prop2: Ah = dinv[n] * sum hs[src] ----------------
__global__ __launch_bounds__(TB) void k_prop2(const int* __restrict__ offsets,
                                              const int* __restrict__ degi,
                                              const int* __restrict__ srcs,
                                              const unsigned short* __restrict__ hs,
                                              const float* __restrict__ dinv,
                                              float* __restrict__ Ah, int N) {
  int tid = blockIdx.x * TB + threadIdx.x;
  int q = tid & 3;
  int n = tid >> 2;
  if (n >= N) return;
  int beg = offsets[n], cnt = degi[n];
  float a[4] = {0.f, 0.f, 0.f, 0.f};
  for (int i = 0; i < cnt; i++) {
    int s = srcs[beg + i];
    uint2 v = *(const uint2*)(hs + (size_t)s * 16 + q * 4);
    a[0] += bflo(v.x); a[1] += bfhi(v.x);
    a[2] += bflo(v.y); a[3] += bfhi(v.y);
  }
  float dvn = dinv[n];
  f4 o = {a[0] * dvn, a[1] * dvn, a[2] * dvn, a[3] * dvn};
  *(f4*)(Ah + (size_t)n * 16 + q * 4) = o;
}

// ---------------- final: out = mean_k relu(Ah@iw2_k + h@rw2_k + b2_k) --------
__global__ __launch_bounds__(TB) void k_final(const float* __restrict__ Ah,
                                              const float* __restrict__ h,
                                              const float* __restrict__ iw2,
                                              const float* __restrict__ rw2,
                                              const float* __restrict__ b2,
                                              float* __restrict__ out, int N) {
  __shared__ float w_iw[2 * 16 * 40];
  __shared__ float w_rw[2 * 16 * 40];
  __shared__ float w_b[2 * 40];
  for (int i = threadIdx.x; i < 1280; i += TB) {
    w_iw[i] = iw2[i];
    w_rw[i] = rw2[i];
  }
  for (int i = threadIdx.x; i < 80; i += TB) w_b[i] = b2[i];
  __syncthreads();

  int idx = blockIdx.x * TB + threadIdx.x;
  if (idx >= N * 40) return;
  int n = idx / 40;
  int o = idx - n * 40;
  float a[16], hr[16];
#pragma unroll
  for (int f = 0; f < 16; f++) {
    a[f] = Ah[(size_t)n * 16 + f];
    hr[f] = h[(size_t)n * 16 + f];
  }
  float res = 0.f;
#pragma unroll
  for (int k = 0; k < 2; k++) {
    float s = w_b[k * 40 + o];
#pragma unroll
    for (int f = 0; f < 16; f++) {
      s += a[f] * w_iw[(k * 16 + f) * 40 + o];
      s += hr[f] * w_rw[(k * 16 + f) * 40 + o];
    }
    res += fmaxf(s, 0.f);
  }
  out[idx] = 0.5f * res;
}

extern "C" void kernel_launch(void* const* d_in, const int* in_sizes, int n_in,
                              void* d_out, int out_size, void* d_ws, size_t ws_size,
                              hipStream_t stream) {
  const float* x = (const float*)d_in[0];
  const int* ei = (const int*)d_in[1];
  const float* iw1 = (const float*)d_in[2];
  const float* rw1 = (const float*)d_in[3];
  const float* b1 = (const float*)d_in[4];
  const float* iw2 = (const float*)d_in[5];
  const float* rw2 = (const float*)d_in[6];
  const float* b2 = (const float*)d_in[7];
  float* out = (float*)d_out;

  const int N = in_sizes[0] / 512;
  const int E = in_sizes[1] / 2;
  const int* src = ei;
  const int* dst = ei + E;
  const int NC = (N + 511) >> 9;  // coarse buckets (<=256 for N<=131072)

  char* base = (char*)d_ws;
  size_t off = 0;
  auto alloc = [&](size_t bytes) -> void* {
    off = (off + 255) & ~(size_t)255;
    void* p = base + off;
    off += bytes;
    return p;
  };
  int* degi = (int*)alloc((size_t)N * 4);
  float* dinv = (float*)alloc((size_t)N * 4);
  int* offsets = (int*)alloc((size_t)N * 4);
  int* ccnt = (int*)alloc(260 * 4);
  int* cbase = (int*)alloc(260 * 4);
  int* ccur = (int*)alloc(260 * 4);
  int2* epairs = (int2*)alloc((size_t)E * 8);
  int* srcs = (int*)alloc((size_t)E * 4);
  unsigned short* Hs = (unsigned short*)alloc((size_t)N * 32 * 2);
  float* hbuf = (float*)alloc((size_t)N * 16 * 4);
  unsigned short* hs = (unsigned short*)alloc((size_t)N * 16 * 2);
  float* Ah = (float*)alloc((size_t)N * 16 * 4);
  short* Whi = (short*)alloc(32768 * 2);
  short* Wlo = (short*)alloc(32768 * 2);
  // R[N,32] fp32 aliases epairs (epairs dead after k_binB; R written after).
  float* R = (float*)epairs;
  (void)ws_size;

  hipMemsetAsync(ccnt, 0, 260 * 4, stream);

  int NBLK = (E + CHA - 1) / CHA;
  k_countA<<<NBLK, TB, 0, stream>>>(dst, ccnt, E);
  k_scanC<<<1, 256, 0, stream>>>(ccnt, cbase, ccur);
  k_binA<<<NBLK, TB, 0, stream>>>(src, dst, ccur, epairs, E);
  k_binB<<<NC, TB, 0, stream>>>(epairs, cbase, degi, offsets, srcs, N);
  k_dinv<<<(N + TB - 1) / TB, TB, 0, stream>>>(degi, dinv, N);
  k_wsplit<<<128, TB, 0, stream>>>(iw1, rw1, Whi, Wlo);
  k_gemm1_mfma<<<(N + 63) / 64, TB, 0, stream>>>(x, Whi, Wlo, dinv, Hs, R, N);
  k_prop1<<<((size_t)N * 4 + TB - 1) / TB, TB, 0, stream>>>(offsets, degi, srcs, Hs, R,
                                                            dinv, b1, hbuf, hs, N);
  k_prop2<<<((size_t)N * 4 + TB - 1) / TB, TB, 0, stream>>>(offsets, degi, srcs, hs,
                                                            dinv, Ah, N);
  k_final<<<((size_t)N * 40 + TB - 1) / TB, TB, 0, stream>>>(Ah, hbuf, iw2, rw2, b2, out, N);
}